// Round 6
// baseline (270.922 us; speedup 1.0000x reference)
//
#include <hip/hip_runtime.h>
#include <hip/hip_bf16.h>
#include <cstdint>
#include <cstddef>

#define NN 50000
#define EE 800000
#define DD 128
#define NEG 0.2f
#define EPSL 1e-5f

// bucket sort config: 64 pass-1 blocks x 12544 edges (64*12544 = 802816 >= EE)
#define NB   64
#define EPB  12544
#define NBKT 196                 // buckets = dst>>8
#define HM   (NBKT * NB)         // 12544
#define SCAP 7168                // LDS staging capacity in bucket_sort (mean 4082, +48 sigma)

#define GROWS 64                 // rows per gemm block
#define AB    (NN / 8)           // gather blocks per column-half (8 nodes each) = 6250

typedef __hip_bfloat16 bf16;
typedef short short8 __attribute__((ext_vector_type(8)));
typedef float f32x4 __attribute__((ext_vector_type(4)));

__device__ inline float bflo(unsigned u) { return __uint_as_float(u << 16); }
__device__ inline float bfhi(unsigned u) { return __uint_as_float(u & 0xffff0000u); }
__device__ inline float bf2f(unsigned short u) { return __uint_as_float((unsigned)u << 16); }

__device__ inline unsigned short f2bf(float f) {
    __bf16 h = (__bf16)f;
    return __builtin_bit_cast(unsigned short, h);
}
__device__ inline unsigned pack2(float a, float b) {
    return (unsigned)f2bf(a) | ((unsigned)f2bf(b) << 16);
}

__device__ inline void store4(float* Out, size_t idx, float4 v) {
    *(float4*)&Out[idx] = v;
}
__device__ inline void store4(bf16* Out, size_t idx, float4 v) {
    union { bf16 b[4]; ushort4 u; } cv;
    cv.b[0] = (bf16)v.x; cv.b[1] = (bf16)v.y; cv.b[2] = (bf16)v.z; cv.b[3] = (bf16)v.w;
    *(ushort4*)&Out[idx] = cv.u;
}

// ================= CSR build: MSD bucket sort (dense writes, no global atomics) ============

// pass A: per-block bucket histogram (int4-vectorized dst reads)
__global__ __launch_bounds__(256) void hist_kernel(const int* __restrict__ ei,
                                                   int* __restrict__ histG) {
    __shared__ int lh[NBKT];
    int tid = threadIdx.x;
    for (int t = tid; t < NBKT; t += 256) lh[t] = 0;
    __syncthreads();
    int base = blockIdx.x * EPB;
    #pragma unroll
    for (int j = 0; j < (EPB + 1023) / 1024; ++j) {
        int off = (j * 256 + tid) * 4;
        if (off < EPB) {
            int i4 = base + off;
            if (i4 < EE) {   // EE % 4 == 0, i4 % 4 == 0 -> full int4 in-bounds
                int4 d4 = *(const int4*)&ei[EE + i4];
                atomicAdd(&lh[(unsigned)d4.x >> 8], 1);
                atomicAdd(&lh[(unsigned)d4.y >> 8], 1);
                atomicAdd(&lh[(unsigned)d4.z >> 8], 1);
                atomicAdd(&lh[(unsigned)d4.w >> 8], 1);
            }
        }
    }
    __syncthreads();
    for (int t = tid; t < NBKT; t += 256) histG[t * NB + blockIdx.x] = lh[t];
}

__global__ __launch_bounds__(1024) void scan_hist_kernel(const int* __restrict__ histG,
                                                         int* __restrict__ offs,
                                                         int* __restrict__ bstart) {
    __shared__ int wsum[16];
    __shared__ int carry_s;
    int tid = threadIdx.x, lane = tid & 63, wv = tid >> 6;
    if (tid == 0) carry_s = 0;
    __syncthreads();
    for (int base = 0; base < HM; base += 4096) {
        int i4 = base + tid * 4;
        int4 v = make_int4(0, 0, 0, 0);
        if (i4 + 3 < HM) v = *(const int4*)&histG[i4];
        else {
            if (i4 + 0 < HM) v.x = histG[i4 + 0];
            if (i4 + 1 < HM) v.y = histG[i4 + 1];
            if (i4 + 2 < HM) v.z = histG[i4 + 2];
            if (i4 + 3 < HM) v.w = histG[i4 + 3];
        }
        int tsum = v.x + v.y + v.z + v.w;
        int x = tsum;
        for (int off = 1; off < 64; off <<= 1) {
            int t = __shfl_up(x, off);
            if (lane >= off) x += t;
        }
        if (lane == 63) wsum[wv] = x;
        __syncthreads();
        if (wv == 0) {
            int s = (lane < 16) ? wsum[lane] : 0;
            for (int off = 1; off < 16; off <<= 1) {
                int t = __shfl_up(s, off);
                if (lane >= off) s += t;
            }
            if (lane < 16) wsum[lane] = s;
        }
        __syncthreads();
        int waveoff = (wv == 0) ? 0 : wsum[wv - 1];
        int carry = carry_s;
        int o0 = carry + waveoff + x - tsum;
        int o1 = o0 + v.x, o2 = o1 + v.y, o3 = o2 + v.z;
        if (i4 + 3 < HM) *(int4*)&offs[i4] = make_int4(o0, o1, o2, o3);
        else {
            if (i4 + 0 < HM) offs[i4 + 0] = o0;
            if (i4 + 1 < HM) offs[i4 + 1] = o1;
            if (i4 + 2 < HM) offs[i4 + 2] = o2;
            if (i4 + 3 < HM) offs[i4 + 3] = o3;
        }
        if (i4 < HM && (i4 % NB) == 0) bstart[i4 / NB] = o0;  // NB % 4 == 0
        __syncthreads();
        if (tid == 0) carry_s += wsum[15];
        __syncthreads();
    }
    if (tid == 0) bstart[NBKT] = carry_s;   // == EE
}

// pass 2: counting sort by dst low byte; ALSO emits row_ptr (the scan IS row_ptr).
// LDS-staged: load bucket slice once (histogram while loading), LDS->LDS scatter, then
// stream col out coalesced. Global-scatter fallback keeps worst-case (bucket > SCAP) correct.
__global__ __launch_bounds__(512) void bucket_sort_kernel(const unsigned* __restrict__ tmp,
                                                          const int* __restrict__ bstart,
                                                          unsigned* __restrict__ col,
                                                          int* __restrict__ row_ptr) {
    __shared__ int cnt[256];
    __shared__ int cpos[256];
    __shared__ int wtot[4];
    __shared__ unsigned stage[SCAP];    // input-order keys
    __shared__ unsigned sorted[SCAP];   // output-order keys
    int tid = threadIdx.x, lane = tid & 63, wv = tid >> 6;
    int s0 = bstart[blockIdx.x], s1 = bstart[blockIdx.x + 1];
    int cntE = s1 - s0;
    bool lds_ok = (cntE <= SCAP);
    for (int t = tid; t < 256; t += 512) cnt[t] = 0;
    __syncthreads();
    if (lds_ok) {
        for (int i = tid; i < cntE; i += 512) {
            unsigned k = tmp[s0 + i];
            stage[i] = k;
            atomicAdd(&cnt[(k >> 16) & 0xFF], 1);
        }
    } else {
        for (int i = s0 + tid; i < s1; i += 512)
            atomicAdd(&cnt[(tmp[i] >> 16) & 0xFF], 1);
    }
    __syncthreads();
    int v = 0, x = 0;
    if (tid < 256) {
        v = cnt[tid];
        x = v;
        for (int off = 1; off < 64; off <<= 1) {
            int t = __shfl_up(x, off);
            if (lane >= off) x += t;
        }
        if (lane == 63) wtot[wv] = x;
    }
    __syncthreads();
    if (tid < 256) {
        int add = 0;
        for (int k = 0; k < wv; ++k) add += wtot[k];
        int start = s0 + add + x - v;
        cpos[tid] = start;
        int d = blockIdx.x * 256 + tid;
        if (d <= NN) row_ptr[d] = start;
    }
    __syncthreads();
    if (lds_ok) {
        for (int i = tid; i < cntE; i += 512) {
            unsigned key = stage[i];
            int pos = atomicAdd(&cpos[(key >> 16) & 0xFF], 1);
            sorted[pos - s0] = key;
        }
        __syncthreads();
        for (int i = tid; i < cntE; i += 512) col[s0 + i] = sorted[i];
    } else {
        for (int i = s0 + tid; i < s1; i += 512) {
            unsigned key = tmp[i];
            int pos = atomicAdd(&cpos[(key >> 16) & 0xFF], 1);
            col[pos] = key;
        }
    }
}

// ================= MFMA GEMM (+optional fused LN1+relu) + attention dots ===================
// 512 threads = 8 waves; 64 rows/block. Wave w: rows (w&3)*16..+16, cols (w>>2)*64..+64.
// mfma_f32_16x16x32_bf16 layouts (HW-verified): A[m=lane&15][k=quad*8+j],
// B[n=lane&15][k=quad*8+j], C/D col=lane&15, row=quad*4+reg.
// LN=true: LN stats computed IN-PROLOGUE from pstats (consumer-side fusion; kernel
// boundary provides visibility — no producer fences, cf. round-1 lesson).
template <int H, bool LN, typename XT>
__device__ __forceinline__ void gemm_attn_body(int gb,
                                               const XT* __restrict__ X,
                                               const float* __restrict__ W,
                                               const float* __restrict__ att_s,
                                               const float* __restrict__ att_d,
                                               const float2* __restrict__ pstats,
                                               const float* __restrict__ lnw,
                                               const float* __restrict__ lnb,
                                               bf16* __restrict__ Hout,
                                               float* __restrict__ a_src,
                                               float* __restrict__ a_dst) {
    __shared__ __align__(16) char lds[(128 * 136 + 64 * 136) * 2 + 2048];  // 54272 B
    unsigned short* Bt = (unsigned short*)lds;                    // [128][136] (W^T)
    unsigned short* As = (unsigned short*)(lds + 128 * 136 * 2);  // [64][136]
    float* Cs = (float*)lds;                                      // [64][132] (reuse)
    float* psum = (float*)(lds + (128 * 136 + 64 * 136) * 2);     // [256] (H==1 combine)
    __shared__ double w1d[8], w2d[8], sred[2];

    int tid = threadIdx.x;
    int lane = tid & 63, w = tid >> 6;    // 8 waves
    int row0 = gb * GROWS;

    // ---- LN stats prologue: issue pstats loads first (long latency, overlaps W-stage) ----
    double s1 = 0.0, s2 = 0.0;
    if (LN) {
        for (int i = tid; i < 2 * AB; i += 512) {
            float2 pv = pstats[i];
            s1 += (double)pv.x; s2 += (double)pv.y;
        }
    }

    // ---- stage W -> Bt transposed: 4 k-consecutive bf16 per b64 write ----
    {
        int c = tid & 127, kg = tid >> 7;   // kg in 0..3
        #pragma unroll 2
        for (int i = 0; i < 8; ++i) {
            int k0 = i * 16 + kg * 4;
            float wa = W[(size_t)(k0 + 0) * DD + c];
            float wb = W[(size_t)(k0 + 1) * DD + c];
            float wcv = W[(size_t)(k0 + 2) * DD + c];
            float wdv = W[(size_t)(k0 + 3) * DD + c];
            uint2 pk = make_uint2(pack2(wa, wb), pack2(wcv, wdv));
            *(uint2*)&Bt[c * 136 + k0] = pk;
        }
    }

    if (LN) {
        #pragma unroll
        for (int off = 32; off; off >>= 1) {
            s1 += __shfl_xor(s1, off);
            s2 += __shfl_xor(s2, off);
        }
        if (lane == 0) { w1d[w] = s1; w2d[w] = s2; }
    }
    __syncthreads();
    if (LN && tid == 0) {
        double a = 0.0, b = 0.0;
        #pragma unroll
        for (int k = 0; k < 8; ++k) { a += w1d[k]; b += w2d[k]; }
        sred[0] = a; sred[1] = b;
    }
    __syncthreads();

    // ---- stage X (+LN+relu) -> As: vector loads, b64 LDS writes ----
    {
        int sub = tid & 31, rq = tid >> 5;  // col-group 0..31, row-slot 0..15
        int c4 = sub * 4;
        float mean = 0.f, inv = 1.f;
        float4 lw4 = make_float4(1.f, 1.f, 1.f, 1.f), lb4 = make_float4(0.f, 0.f, 0.f, 0.f);
        if (LN) {
            const double M = (double)NN * DD;
            double mean_d = sred[0] / M;
            double var_d = sred[1] / M - mean_d * mean_d;
            mean = (float)mean_d;
            inv = rsqrtf((float)var_d + EPSL);
            lw4 = *(const float4*)&lnw[c4];
            lb4 = *(const float4*)&lnb[c4];
        }
        #pragma unroll
        for (int i = 0; i < 4; ++i) {
            int r = i * 16 + rq;
            int row = row0 + r;
            float4 xv = make_float4(0.f, 0.f, 0.f, 0.f);
            if (row < NN) {
                if constexpr (sizeof(XT) == 4) {
                    xv = *(const float4*)&((const float*)X)[(size_t)row * DD + c4];
                } else {
                    ushort4 xb = *(const ushort4*)&((const unsigned short*)X)[(size_t)row * DD + c4];
                    xv = make_float4(bf2f(xb.x), bf2f(xb.y), bf2f(xb.z), bf2f(xb.w));
                }
            }
            if (LN) {
                xv.x = fmaxf((xv.x - mean) * inv * lw4.x + lb4.x, 0.f);
                xv.y = fmaxf((xv.y - mean) * inv * lw4.y + lb4.y, 0.f);
                xv.z = fmaxf((xv.z - mean) * inv * lw4.z + lb4.z, 0.f);
                xv.w = fmaxf((xv.w - mean) * inv * lw4.w + lb4.w, 0.f);
            }
            uint2 pk = make_uint2(pack2(xv.x, xv.y), pack2(xv.z, xv.w));
            *(uint2*)&As[r * 136 + c4] = pk;
        }
    }
    __syncthreads();

    int rg = w & 3, cg = w >> 2;          // row-group, col-group
    int l15 = lane & 15, quad = lane >> 4;
    f32x4 acc[4];
    #pragma unroll
    for (int t = 0; t < 4; ++t) acc[t] = 0.f;
    const unsigned short* Arow = As + (rg * 16 + l15) * 136 + quad * 8;
    const unsigned short* Brow = Bt + l15 * 136 + quad * 8;
    #pragma unroll
    for (int ks = 0; ks < 4; ++ks) {
        short8 a = *(const short8*)(Arow + ks * 32);
        #pragma unroll
        for (int tt = 0; tt < 4; ++tt) {
            short8 b = *(const short8*)(Brow + (cg * 4 + tt) * 16 * 136 + ks * 32);
            acc[tt] = __builtin_amdgcn_mfma_f32_16x16x32_bf16(a, b, acc[tt], 0, 0, 0);
        }
    }
    __syncthreads();   // all waves done reading Bt/As; Cs may overwrite

    #pragma unroll
    for (int tt = 0; tt < 4; ++tt)
        #pragma unroll
        for (int r = 0; r < 4; ++r)
            Cs[(rg * 16 + quad * 4 + r) * 132 + (cg * 4 + tt) * 16 + l15] = acc[tt][r];

    // attention dots: wave covers cols (cg*4+tt)*16+l15; for H=2 head == cg exactly
    float ds[4] = {0.f, 0.f, 0.f, 0.f}, dd[4] = {0.f, 0.f, 0.f, 0.f};
    #pragma unroll
    for (int tt = 0; tt < 4; ++tt) {
        int cc = (cg * 4 + tt) * 16 + l15;
        float as_ = att_s[cc], ad_ = att_d[cc];
        #pragma unroll
        for (int r = 0; r < 4; ++r) {
            ds[r] = fmaf(acc[tt][r], as_, ds[r]);
            dd[r] = fmaf(acc[tt][r], ad_, dd[r]);
        }
    }
    #pragma unroll
    for (int off = 1; off < 16; off <<= 1) {
        #pragma unroll
        for (int r = 0; r < 4; ++r) {
            ds[r] += __shfl_xor(ds[r], off);
            dd[r] += __shfl_xor(dd[r], off);
        }
    }
    if (l15 == 0) {
        #pragma unroll
        for (int r = 0; r < 4; ++r) {
            int rr = rg * 16 + quad * 4 + r;
            int row = row0 + rr;
            if (H == 2) {
                if (row < NN) {
                    a_src[row * 2 + cg] = ds[r];
                    a_dst[row * 2 + cg] = dd[r];
                }
            } else {
                psum[cg * 64 + rr] = ds[r];
                psum[128 + cg * 64 + rr] = dd[r];
            }
        }
    }
    __syncthreads();

    if (H == 1 && tid < 64) {
        int row = row0 + tid;
        if (row < NN) {
            a_src[row] = psum[tid] + psum[64 + tid];
            a_dst[row] = psum[128 + tid] + psum[192 + tid];
        }
    }

    // ---- coalesced readout: float4 LDS reads, ushort4 global stores ----
    {
        int sub = tid & 31, rq = tid >> 5;
        int c4 = sub * 4;
        unsigned short* Hp = (unsigned short*)Hout;
        #pragma unroll
        for (int i = 0; i < 4; ++i) {
            int r = i * 16 + rq;
            int row = row0 + r;
            if (row < NN) {
                float4 cv = *(const float4*)&Cs[r * 132 + c4];
                ushort4 pk;
                pk.x = f2bf(cv.x); pk.y = f2bf(cv.y);
                pk.z = f2bf(cv.z); pk.w = f2bf(cv.w);
                *(ushort4*)&Hp[(size_t)row * DD + c4] = pk;
            }
        }
    }
}

template <int H, bool LN, typename XT>
__global__ __launch_bounds__(512) void gemm_attn(const XT* __restrict__ X,
                                                 const float* __restrict__ W,
                                                 const float* __restrict__ att_s,
                                                 const float* __restrict__ att_d,
                                                 const float2* __restrict__ pstats,
                                                 const float* __restrict__ lnw,
                                                 const float* __restrict__ lnb,
                                                 bf16* __restrict__ Hout,
                                                 float* __restrict__ a_src,
                                                 float* __restrict__ a_dst) {
    gemm_attn_body<H, LN, XT>(blockIdx.x, X, W, att_s, att_d, pstats, lnw, lnb,
                              Hout, a_src, a_dst);
}

// ===== fused: CSR scatter pass-1 (blocks 0..NB-1) || layer-1 GEMM (blocks NB..NB+GB-1) =====
// The two are data-independent. Branch is block-uniform so per-branch barriers are safe.
__global__ __launch_bounds__(512) void scatter_gemm1(const int* __restrict__ ei,
                                                     const int* __restrict__ offs,
                                                     unsigned* __restrict__ tmp,
                                                     const float* __restrict__ X,
                                                     const float* __restrict__ W,
                                                     const float* __restrict__ att_s,
                                                     const float* __restrict__ att_d,
                                                     bf16* __restrict__ Hout,
                                                     float* __restrict__ a_src,
                                                     float* __restrict__ a_dst) {
    if (blockIdx.x < NB) {
        __shared__ int lofs[NBKT];
        int tid = threadIdx.x;
        for (int t = tid; t < NBKT; t += 512) lofs[t] = offs[t * NB + blockIdx.x];
        __syncthreads();
        int base = blockIdx.x * EPB;
        #pragma unroll
        for (int j = 0; j < (EPB + 2047) / 2048; ++j) {
            int off = (j * 512 + tid) * 4;
            if (off < EPB) {
                int i4 = base + off;
                if (i4 < EE) {
                    int4 s4 = *(const int4*)&ei[i4];
                    int4 d4 = *(const int4*)&ei[EE + i4];
                    unsigned k0 = ((unsigned)d4.x << 16) | (unsigned)s4.x;
                    unsigned k1 = ((unsigned)d4.y << 16) | (unsigned)s4.y;
                    unsigned k2 = ((unsigned)d4.z << 16) | (unsigned)s4.z;
                    unsigned k3 = ((unsigned)d4.w << 16) | (unsigned)s4.w;
                    tmp[atomicAdd(&lofs[(unsigned)d4.x >> 8], 1)] = k0;
                    tmp[atomicAdd(&lofs[(unsigned)d4.y >> 8], 1)] = k1;
                    tmp[atomicAdd(&lofs[(unsigned)d4.z >> 8], 1)] = k2;
                    tmp[atomicAdd(&lofs[(unsigned)d4.w >> 8], 1)] = k3;
                }
            }
        }
    } else {
        gemm_attn_body<2, false, float>(blockIdx.x - NB, X, W, att_s, att_d,
                                        nullptr, nullptr, nullptr, Hout, a_src, a_dst);
    }
}

// ============ GAT softmax + aggregate: COLUMN-HALF PHASED gather ==============
// Round-6: grid = 2*AB. Blocks [0,AB) process cols 0-63, [AB,2AB) cols 64-127.
// Working set per phase = 6.4 MB (vs 12.8) -> higher per-XCD L2 hit rate; HW dispatch
// order gives soft device-level phase separation with zero extra launches.
// For H=2 the column half IS the head (cols 0-63 head0, 64-127 head1) -> each phase
// computes only its head's softmax. Lane sl&15 owns 4 cols (uint2 loads); parity
// sl>>4 owns alternating edges; cross-parity shfl_xor(16) sum; half==0 lanes store.
// pstats: one float2 per block (2*AB entries); consumers sum all (no producer fences).
template <int H, typename OT>
__global__ __launch_bounds__(256) void gat_agg(const int* __restrict__ row_ptr,
                                               const unsigned* __restrict__ col,
                                               const bf16* __restrict__ Hin,
                                               const float* __restrict__ a_src,
                                               const float* __restrict__ a_dst,
                                               const float* __restrict__ bias,
                                               OT* __restrict__ Out,
                                               float2* __restrict__ pstats) {
    int tid = threadIdx.x;
    int sl = tid & 31;
    int hw = tid >> 5;
    int ch = (blockIdx.x < AB) ? 0 : 1;            // column half (== head for H=2)
    int blk = blockIdx.x - ch * AB;
    int n = blk * 8 + hw;
    int half = sl >> 4;                            // edge parity owned by this lane
    int c4 = ch * 64 + (sl & 15) * 4;              // 4 cols per lane

    int beg = row_ptr[n], end = row_ptr[n + 1];
    int deg = end - beg;

    float ad = a_dst[n * H + ((H == 2) ? ch : 0)];
    const ushort* Hp = (const ushort*)Hin + c4;

    float acc[4] = {0.f, 0.f, 0.f, 0.f};
    float dl = 0.f;

    for (int base = 0; base < deg; base += 32) {
        int ecnt = min(32, deg - base);
        int sv = 0; float wv = 0.f;
        if (sl < ecnt) {
            sv = (int)(col[beg + base + sl] & 0xffffu);
            float as_ = (H == 2) ? a_src[sv * 2 + ch] : a_src[sv];
            float e = as_ + ad; e = (e > 0.f) ? e : NEG * e;
            wv = __expf(e);
            dl += wv;
        }
        int ecnt16 = (ecnt + 15) & ~15;   // 16 or 32; padding: sv=0 (hot row), w=0 (exact)
        for (int j = 0; j < ecnt16; j += 16) {
            int s[8]; uint2 h[8]; float ww[8];
            #pragma unroll
            for (int q = 0; q < 8; ++q) s[q] = __shfl(sv, j + 2 * q + half, 32);
            #pragma unroll
            for (int q = 0; q < 8; ++q) h[q] = *(const uint2*)(Hp + (size_t)s[q] * DD);
            #pragma unroll
            for (int q = 0; q < 8; ++q) ww[q] = __shfl(wv, j + 2 * q + half, 32);
            #pragma unroll
            for (int q = 0; q < 8; ++q) {
                acc[0] = fmaf(ww[q], bflo(h[q].x), acc[0]);
                acc[1] = fmaf(ww[q], bfhi(h[q].x), acc[1]);
                acc[2] = fmaf(ww[q], bflo(h[q].y), acc[2]);
                acc[3] = fmaf(ww[q], bfhi(h[q].y), acc[3]);
            }
        }
    }

    // cross-parity sum: lanes sl and sl^16 cover same cols, complementary edges
    #pragma unroll
    for (int k = 0; k < 4; ++k) acc[k] += __shfl_xor(acc[k], 16, 32);

    #pragma unroll
    for (int off = 1; off < 32; off <<= 1) dl += __shfl_xor(dl, off);

    // implicit self-loop
    float es = a_src[n * H + ((H == 2) ? ch : 0)] + ad;
    es = (es > 0.f) ? es : NEG * es;
    float ws = __expf(es);
    float rinv = 1.f / (dl + ws + 1e-16f);
    uint2 hs = *(const uint2*)(Hp + (size_t)n * DD);
    acc[0] = fmaf(ws, bflo(hs.x), acc[0]);
    acc[1] = fmaf(ws, bfhi(hs.x), acc[1]);
    acc[2] = fmaf(ws, bflo(hs.y), acc[2]);
    acc[3] = fmaf(ws, bfhi(hs.y), acc[3]);

    float t1 = 0.f, t2 = 0.f;
    if (half == 0) {
        float4 bi = *(const float4*)&bias[c4];
        float4 o;
        o.x = acc[0] * rinv + bi.x;
        o.y = acc[1] * rinv + bi.y;
        o.z = acc[2] * rinv + bi.z;
        o.w = acc[3] * rinv + bi.w;
        store4(Out, (size_t)n * DD + c4, o);
        t1 = o.x + o.y + o.z + o.w;
        t2 = o.x * o.x + o.y * o.y + o.z * o.z + o.w * o.w;
    }
    #pragma unroll
    for (int off = 1; off < 32; off <<= 1) {
        t1 += __shfl_xor(t1, off);
        t2 += __shfl_xor(t2, off);
    }
    __shared__ float2 ps[8];
    if (sl == 0) ps[hw] = make_float2(t1, t2);
    __syncthreads();
    if (tid == 0) {
        float a = 0.f, b = 0.f;
        #pragma unroll
        for (int k = 0; k < 8; ++k) { a += ps[k].x; b += ps[k].y; }
        pstats[blockIdx.x] = make_float2(a, b);
    }
}

// -------- deterministic single-block reduce of per-BLOCK LN partials (2*AB entries) -------
__global__ __launch_bounds__(1024) void reduce_stats_kernel(const float2* __restrict__ pstats,
                                                            double* __restrict__ stats) {
    int tid = threadIdx.x, lane = tid & 63, wv = tid >> 6;
    double s1 = 0.0, s2 = 0.0;
    for (int i = tid; i < 2 * AB; i += 1024) {
        float2 v = pstats[i];
        s1 += (double)v.x; s2 += (double)v.y;
    }
    for (int off = 32; off; off >>= 1) {
        s1 += __shfl_xor(s1, off);
        s2 += __shfl_xor(s2, off);
    }
    __shared__ double w1[16], w2[16];
    if (lane == 0) { w1[wv] = s1; w2[wv] = s2; }
    __syncthreads();
    if (tid == 0) {
        double a = 0.0, b = 0.0;
        for (int i = 0; i < 16; ++i) { a += w1[i]; b += w2[i]; }
        stats[0] = a; stats[1] = b;
    }
}

// ======== SimpleConv(mean) + LN2 affine + residual + relu: COLUMN-HALF PHASED =============
// Same round-6 structure as gat_agg (ww = 1 real / 0 pad; denominator = deg per phase).
__global__ __launch_bounds__(256) void simpleconv_kernel(const int* __restrict__ row_ptr,
                                                         const unsigned* __restrict__ col,
                                                         const bf16* __restrict__ Hin,
                                                         const float* __restrict__ X,
                                                         const double* __restrict__ stats,
                                                         const float* __restrict__ lnw,
                                                         const float* __restrict__ lnb,
                                                         float* __restrict__ Out) {
    int tid = threadIdx.x;
    int sl = tid & 31;
    int hw = tid >> 5;
    int ch = (blockIdx.x < AB) ? 0 : 1;
    int blk = blockIdx.x - ch * AB;
    int n = blk * 8 + hw;
    int half = sl >> 4;
    int c4 = ch * 64 + (sl & 15) * 4;
    int beg = row_ptr[n], end = row_ptr[n + 1];
    int deg = end - beg;
    const ushort* Hp = (const ushort*)Hin + c4;

    float acc[4] = {0.f, 0.f, 0.f, 0.f};
    for (int base = 0; base < deg; base += 32) {
        int ecnt = min(32, deg - base);
        int sv = 0;
        if (sl < ecnt) sv = (int)(col[beg + base + sl] & 0xffffu);
        int ecnt16 = (ecnt + 15) & ~15;
        for (int j = 0; j < ecnt16; j += 16) {
            int s[8]; uint2 h[8];
            #pragma unroll
            for (int q = 0; q < 8; ++q) s[q] = __shfl(sv, j + 2 * q + half, 32);
            #pragma unroll
            for (int q = 0; q < 8; ++q) h[q] = *(const uint2*)(Hp + (size_t)s[q] * DD);
            #pragma unroll
            for (int q = 0; q < 8; ++q) {
                float ww = (j + 2 * q + half < ecnt) ? 1.f : 0.f;
                acc[0] = fmaf(ww, bflo(h[q].x), acc[0]);
                acc[1] = fmaf(ww, bfhi(h[q].x), acc[1]);
                acc[2] = fmaf(ww, bflo(h[q].y), acc[2]);
                acc[3] = fmaf(ww, bfhi(h[q].y), acc[3]);
            }
        }
    }

    // cross-parity sum
    #pragma unroll
    for (int k = 0; k < 4; ++k) acc[k] += __shfl_xor(acc[k], 16, 32);

    if (half == 0) {
        const double M = (double)NN * DD;
        double mean_d = stats[0] / M;
        double var_d = stats[1] / M - mean_d * mean_d;
        float mean2 = (float)mean_d;
        float inv2 = rsqrtf((float)var_d + EPSL);
        float rc = 1.f / (float)((deg > 0) ? deg : 1);
        float4 xr = *(const float4*)&X[(size_t)n * DD + c4];
        float4 o;
        if (deg > 0) {
            float4 lw = *(const float4*)&lnw[c4];
            float4 lb = *(const float4*)&lnb[c4];
            o.x = (acc[0] * rc - mean2) * inv2 * lw.x + lb.x;
            o.y = (acc[1] * rc - mean2) * inv2 * lw.y + lb.y;
            o.z = (acc[2] * rc - mean2) * inv2 * lw.z + lb.z;
            o.w = (acc[3] * rc - mean2) * inv2 * lw.w + lb.w;
        } else {
            o.x = o.y = o.z = o.w = 0.f;
        }
        o.x = fmaxf(o.x + xr.x, 0.f);
        o.y = fmaxf(o.y + xr.y, 0.f);
        o.z = fmaxf(o.z + xr.z, 0.f);
        o.w = fmaxf(o.w + xr.w, 0.f);
        *(float4*)&Out[(size_t)n * DD + c4] = o;
    }
}

extern "C" void kernel_launch(void* const* d_in, const int* in_sizes, int n_in,
                              void* d_out, int out_size, void* d_ws, size_t ws_size,
                              hipStream_t stream) {
    const float* x    = (const float*)d_in[0];
    const int*   ei   = (const int*)d_in[1];
    const float* W1   = (const float*)d_in[2];
    const float* as1  = (const float*)d_in[3];
    const float* ad1  = (const float*)d_in[4];
    const float* b1   = (const float*)d_in[5];
    const float* ln1w = (const float*)d_in[6];
    const float* ln1b = (const float*)d_in[7];
    const float* W2   = (const float*)d_in[8];
    const float* as2  = (const float*)d_in[9];
    const float* ad2  = (const float*)d_in[10];
    const float* b2   = (const float*)d_in[11];
    const float* ln2w = (const float*)d_in[12];
    const float* ln2b = (const float*)d_in[13];
    float* out = (float*)d_out;

    char* p = (char*)d_ws;
    auto alloc = [&](size_t bytes) {
        void* r = (void*)p;
        p += (bytes + 255) & ~(size_t)255;
        return r;
    };
    unsigned* tmp     = (unsigned*)alloc((size_t)EE * 4);
    unsigned* col     = (unsigned*)alloc((size_t)EE * 4);
    int*      histG   = (int*)alloc((size_t)HM * 4);
    int*      offs    = (int*)alloc((size_t)HM * 4);
    int*      bstart  = (int*)alloc((size_t)(NBKT + 1) * 4);
    int*      row_ptr = (int*)alloc((size_t)(NN + 256) * 4);
    double*   stats2  = (double*)alloc(16);
    float2*   pstats  = (float2*)alloc((size_t)2 * AB * 8);
    bf16*     bufA    = (bf16*)alloc((size_t)NN * DD * 2);   // h1, later h2
    bf16*     bufB    = (bf16*)alloc((size_t)NN * DD * 2);   // out1, later out2
    float*    aS1     = (float*)alloc((size_t)NN * 2 * 4);
    float*    aD1     = (float*)alloc((size_t)NN * 2 * 4);
    float*    aS2     = (float*)alloc((size_t)NN * 4);
    float*    aD2     = (float*)alloc((size_t)NN * 4);

    const int GB = (NN + GROWS - 1) / GROWS;   // 782

    // ---- CSR build (bucket sort); gemm1 overlapped with scatter pass ----
    hist_kernel<<<NB, 256, 0, stream>>>(ei, histG);
    scan_hist_kernel<<<1, 1024, 0, stream>>>(histG, offs, bstart);
    scatter_gemm1<<<NB + GB, 512, 0, stream>>>(ei, offs, tmp,
                                               x, W1, as1, ad1, bufA, aS1, aD1);
    bucket_sort_kernel<<<NBKT, 512, 0, stream>>>(tmp, bstart, col, row_ptr);

    // layer 1 aggregate: GATConv(128 -> 64, heads=2, concat); column-half phased
    gat_agg<2, bf16><<<2 * AB, 256, 0, stream>>>(row_ptr, col, bufA, aS1, aD1, b1,
                                                 bufB, pstats);

    // layer 2: GATConv(128 -> 128, heads=1); LN1 stats reduced in-prologue from pstats
    gemm_attn<1, true, bf16><<<GB, 512, 0, stream>>>(bufB, W2, as2, ad2,
                                                     pstats, ln1w, ln1b,
                                                     bufA, aS2, aD2);
    gat_agg<1, bf16><<<2 * AB, 256, 0, stream>>>(row_ptr, col, bufA, aS2, aD2, b2,
                                                 bufB, pstats);
    reduce_stats_kernel<<<1, 1024, 0, stream>>>(pstats, stats2);

    // SimpleConv mean over original edges + LN2 affine + residual + relu (fused)
    simpleconv_kernel<<<2 * AB, 256, 0, stream>>>(row_ptr, col, bufB, x,
                                                  stats2, ln2w, ln2b, out);
}

// Round 7
// 257.556 us; speedup vs baseline: 1.0519x; 1.0519x over previous
//
#include <hip/hip_runtime.h>
#include <hip/hip_bf16.h>
#include <cstdint>
#include <cstddef>

#define NN 50000
#define EE 800000
#define DD 128
#define NEG 0.2f
#define EPSL 1e-5f

// bucket sort config: 64 pass-1 blocks x 12544 edges (64*12544 = 802816 >= EE)
#define NB   64
#define EPB  12544
#define NBKT 196                 // buckets = dst>>8
#define HM   (NBKT * NB)         // 12544
#define SCAP 7168                // LDS staging capacity in bucket_sort (mean 4082, +48 sigma)

#define GROWS 64                 // rows per gemm block
#define AB    (NN / 8)           // gat_agg blocks (8 nodes each) = 6250

typedef __hip_bfloat16 bf16;
typedef short short8 __attribute__((ext_vector_type(8)));
typedef float f32x4 __attribute__((ext_vector_type(4)));

__device__ inline float bflo(unsigned u) { return __uint_as_float(u << 16); }
__device__ inline float bfhi(unsigned u) { return __uint_as_float(u & 0xffff0000u); }
__device__ inline float bf2f(unsigned short u) { return __uint_as_float((unsigned)u << 16); }

__device__ inline unsigned short f2bf(float f) {
    __bf16 h = (__bf16)f;
    return __builtin_bit_cast(unsigned short, h);
}
__device__ inline unsigned pack2(float a, float b) {
    return (unsigned)f2bf(a) | ((unsigned)f2bf(b) << 16);
}

__device__ inline void store4(float* Out, size_t idx, float4 v) {
    *(float4*)&Out[idx] = v;
}
__device__ inline void store4(bf16* Out, size_t idx, float4 v) {
    union { bf16 b[4]; ushort4 u; } cv;
    cv.b[0] = (bf16)v.x; cv.b[1] = (bf16)v.y; cv.b[2] = (bf16)v.z; cv.b[3] = (bf16)v.w;
    *(ushort4*)&Out[idx] = cv.u;
}

// ================= CSR build: MSD bucket sort (dense writes, no global atomics) ============

// pass A: per-block bucket histogram (int4-vectorized dst reads)
__global__ __launch_bounds__(256) void hist_kernel(const int* __restrict__ ei,
                                                   int* __restrict__ histG) {
    __shared__ int lh[NBKT];
    int tid = threadIdx.x;
    for (int t = tid; t < NBKT; t += 256) lh[t] = 0;
    __syncthreads();
    int base = blockIdx.x * EPB;
    #pragma unroll
    for (int j = 0; j < (EPB + 1023) / 1024; ++j) {
        int off = (j * 256 + tid) * 4;
        if (off < EPB) {
            int i4 = base + off;
            if (i4 < EE) {   // EE % 4 == 0, i4 % 4 == 0 -> full int4 in-bounds
                int4 d4 = *(const int4*)&ei[EE + i4];
                atomicAdd(&lh[(unsigned)d4.x >> 8], 1);
                atomicAdd(&lh[(unsigned)d4.y >> 8], 1);
                atomicAdd(&lh[(unsigned)d4.z >> 8], 1);
                atomicAdd(&lh[(unsigned)d4.w >> 8], 1);
            }
        }
    }
    __syncthreads();
    for (int t = tid; t < NBKT; t += 256) histG[t * NB + blockIdx.x] = lh[t];
}

__global__ __launch_bounds__(1024) void scan_hist_kernel(const int* __restrict__ histG,
                                                         int* __restrict__ offs,
                                                         int* __restrict__ bstart) {
    __shared__ int wsum[16];
    __shared__ int carry_s;
    int tid = threadIdx.x, lane = tid & 63, wv = tid >> 6;
    if (tid == 0) carry_s = 0;
    __syncthreads();
    for (int base = 0; base < HM; base += 4096) {
        int i4 = base + tid * 4;
        int4 v = make_int4(0, 0, 0, 0);
        if (i4 + 3 < HM) v = *(const int4*)&histG[i4];
        else {
            if (i4 + 0 < HM) v.x = histG[i4 + 0];
            if (i4 + 1 < HM) v.y = histG[i4 + 1];
            if (i4 + 2 < HM) v.z = histG[i4 + 2];
            if (i4 + 3 < HM) v.w = histG[i4 + 3];
        }
        int tsum = v.x + v.y + v.z + v.w;
        int x = tsum;
        for (int off = 1; off < 64; off <<= 1) {
            int t = __shfl_up(x, off);
            if (lane >= off) x += t;
        }
        if (lane == 63) wsum[wv] = x;
        __syncthreads();
        if (wv == 0) {
            int s = (lane < 16) ? wsum[lane] : 0;
            for (int off = 1; off < 16; off <<= 1) {
                int t = __shfl_up(s, off);
                if (lane >= off) s += t;
            }
            if (lane < 16) wsum[lane] = s;
        }
        __syncthreads();
        int waveoff = (wv == 0) ? 0 : wsum[wv - 1];
        int carry = carry_s;
        int o0 = carry + waveoff + x - tsum;
        int o1 = o0 + v.x, o2 = o1 + v.y, o3 = o2 + v.z;
        if (i4 + 3 < HM) *(int4*)&offs[i4] = make_int4(o0, o1, o2, o3);
        else {
            if (i4 + 0 < HM) offs[i4 + 0] = o0;
            if (i4 + 1 < HM) offs[i4 + 1] = o1;
            if (i4 + 2 < HM) offs[i4 + 2] = o2;
            if (i4 + 3 < HM) offs[i4 + 3] = o3;
        }
        if (i4 < HM && (i4 % NB) == 0) bstart[i4 / NB] = o0;  // NB % 4 == 0
        __syncthreads();
        if (tid == 0) carry_s += wsum[15];
        __syncthreads();
    }
    if (tid == 0) bstart[NBKT] = carry_s;   // == EE
}

// pass 2: counting sort by dst low byte; ALSO emits row_ptr (the scan IS row_ptr).
// LDS-staged: load bucket slice once (histogram while loading), LDS->LDS scatter, then
// stream col out coalesced. Global-scatter fallback keeps worst-case (bucket > SCAP) correct.
__global__ __launch_bounds__(512) void bucket_sort_kernel(const unsigned* __restrict__ tmp,
                                                          const int* __restrict__ bstart,
                                                          unsigned* __restrict__ col,
                                                          int* __restrict__ row_ptr) {
    __shared__ int cnt[256];
    __shared__ int cpos[256];
    __shared__ int wtot[4];
    __shared__ unsigned stage[SCAP];    // input-order keys
    __shared__ unsigned sorted[SCAP];   // output-order keys
    int tid = threadIdx.x, lane = tid & 63, wv = tid >> 6;
    int s0 = bstart[blockIdx.x], s1 = bstart[blockIdx.x + 1];
    int cntE = s1 - s0;
    bool lds_ok = (cntE <= SCAP);
    for (int t = tid; t < 256; t += 512) cnt[t] = 0;
    __syncthreads();
    if (lds_ok) {
        for (int i = tid; i < cntE; i += 512) {
            unsigned k = tmp[s0 + i];
            stage[i] = k;
            atomicAdd(&cnt[(k >> 16) & 0xFF], 1);
        }
    } else {
        for (int i = s0 + tid; i < s1; i += 512)
            atomicAdd(&cnt[(tmp[i] >> 16) & 0xFF], 1);
    }
    __syncthreads();
    int v = 0, x = 0;
    if (tid < 256) {
        v = cnt[tid];
        x = v;
        for (int off = 1; off < 64; off <<= 1) {
            int t = __shfl_up(x, off);
            if (lane >= off) x += t;
        }
        if (lane == 63) wtot[wv] = x;
    }
    __syncthreads();
    if (tid < 256) {
        int add = 0;
        for (int k = 0; k < wv; ++k) add += wtot[k];
        int start = s0 + add + x - v;
        cpos[tid] = start;
        int d = blockIdx.x * 256 + tid;
        if (d <= NN) row_ptr[d] = start;
    }
    __syncthreads();
    if (lds_ok) {
        for (int i = tid; i < cntE; i += 512) {
            unsigned key = stage[i];
            int pos = atomicAdd(&cpos[(key >> 16) & 0xFF], 1);
            sorted[pos - s0] = key;
        }
        __syncthreads();
        for (int i = tid; i < cntE; i += 512) col[s0 + i] = sorted[i];
    } else {
        for (int i = s0 + tid; i < s1; i += 512) {
            unsigned key = tmp[i];
            int pos = atomicAdd(&cpos[(key >> 16) & 0xFF], 1);
            col[pos] = key;
        }
    }
}

// ================= MFMA GEMM (+optional fused LN1+relu) + attention dots ===================
// 512 threads = 8 waves; 64 rows/block. Wave w: rows (w&3)*16..+16, cols (w>>2)*64..+64.
// mfma_f32_16x16x32_bf16 layouts (HW-verified): A[m=lane&15][k=quad*8+j],
// B[n=lane&15][k=quad*8+j], C/D col=lane&15, row=quad*4+reg.
// LN=true: LN stats computed IN-PROLOGUE from pstats (consumer-side fusion; kernel
// boundary provides visibility — no producer fences, cf. round-1 lesson).
template <int H, bool LN, typename XT>
__device__ __forceinline__ void gemm_attn_body(int gb,
                                               const XT* __restrict__ X,
                                               const float* __restrict__ W,
                                               const float* __restrict__ att_s,
                                               const float* __restrict__ att_d,
                                               const float2* __restrict__ pstats,
                                               const float* __restrict__ lnw,
                                               const float* __restrict__ lnb,
                                               bf16* __restrict__ Hout,
                                               float* __restrict__ a_src,
                                               float* __restrict__ a_dst) {
    __shared__ __align__(16) char lds[(128 * 136 + 64 * 136) * 2 + 2048];  // 54272 B
    unsigned short* Bt = (unsigned short*)lds;                    // [128][136] (W^T)
    unsigned short* As = (unsigned short*)(lds + 128 * 136 * 2);  // [64][136]
    float* Cs = (float*)lds;                                      // [64][132] (reuse)
    float* psum = (float*)(lds + (128 * 136 + 64 * 136) * 2);     // [256] (H==1 combine)
    __shared__ double w1d[8], w2d[8], sred[2];

    int tid = threadIdx.x;
    int lane = tid & 63, w = tid >> 6;    // 8 waves
    int row0 = gb * GROWS;

    // ---- LN stats prologue: issue pstats loads first (long latency, overlaps W-stage) ----
    double s1 = 0.0, s2 = 0.0;
    if (LN) {
        for (int i = tid; i < AB; i += 512) {
            float2 pv = pstats[i];
            s1 += (double)pv.x; s2 += (double)pv.y;
        }
    }

    // ---- stage W -> Bt transposed: 4 k-consecutive bf16 per b64 write ----
    {
        int c = tid & 127, kg = tid >> 7;   // kg in 0..3
        #pragma unroll 2
        for (int i = 0; i < 8; ++i) {
            int k0 = i * 16 + kg * 4;
            float wa = W[(size_t)(k0 + 0) * DD + c];
            float wb = W[(size_t)(k0 + 1) * DD + c];
            float wcv = W[(size_t)(k0 + 2) * DD + c];
            float wdv = W[(size_t)(k0 + 3) * DD + c];
            uint2 pk = make_uint2(pack2(wa, wb), pack2(wcv, wdv));
            *(uint2*)&Bt[c * 136 + k0] = pk;
        }
    }

    if (LN) {
        #pragma unroll
        for (int off = 32; off; off >>= 1) {
            s1 += __shfl_xor(s1, off);
            s2 += __shfl_xor(s2, off);
        }
        if (lane == 0) { w1d[w] = s1; w2d[w] = s2; }
    }
    __syncthreads();
    if (LN && tid == 0) {
        double a = 0.0, b = 0.0;
        #pragma unroll
        for (int k = 0; k < 8; ++k) { a += w1d[k]; b += w2d[k]; }
        sred[0] = a; sred[1] = b;
    }
    __syncthreads();

    // ---- stage X (+LN+relu) -> As: vector loads, b64 LDS writes ----
    {
        int sub = tid & 31, rq = tid >> 5;  // col-group 0..31, row-slot 0..15
        int c4 = sub * 4;
        float mean = 0.f, inv = 1.f;
        float4 lw4 = make_float4(1.f, 1.f, 1.f, 1.f), lb4 = make_float4(0.f, 0.f, 0.f, 0.f);
        if (LN) {
            const double M = (double)NN * DD;
            double mean_d = sred[0] / M;
            double var_d = sred[1] / M - mean_d * mean_d;
            mean = (float)mean_d;
            inv = rsqrtf((float)var_d + EPSL);
            lw4 = *(const float4*)&lnw[c4];
            lb4 = *(const float4*)&lnb[c4];
        }
        #pragma unroll
        for (int i = 0; i < 4; ++i) {
            int r = i * 16 + rq;
            int row = row0 + r;
            float4 xv = make_float4(0.f, 0.f, 0.f, 0.f);
            if (row < NN) {
                if constexpr (sizeof(XT) == 4) {
                    xv = *(const float4*)&((const float*)X)[(size_t)row * DD + c4];
                } else {
                    ushort4 xb = *(const ushort4*)&((const unsigned short*)X)[(size_t)row * DD + c4];
                    xv = make_float4(bf2f(xb.x), bf2f(xb.y), bf2f(xb.z), bf2f(xb.w));
                }
            }
            if (LN) {
                xv.x = fmaxf((xv.x - mean) * inv * lw4.x + lb4.x, 0.f);
                xv.y = fmaxf((xv.y - mean) * inv * lw4.y + lb4.y, 0.f);
                xv.z = fmaxf((xv.z - mean) * inv * lw4.z + lb4.z, 0.f);
                xv.w = fmaxf((xv.w - mean) * inv * lw4.w + lb4.w, 0.f);
            }
            uint2 pk = make_uint2(pack2(xv.x, xv.y), pack2(xv.z, xv.w));
            *(uint2*)&As[r * 136 + c4] = pk;
        }
    }
    __syncthreads();

    int rg = w & 3, cg = w >> 2;          // row-group, col-group
    int l15 = lane & 15, quad = lane >> 4;
    f32x4 acc[4];
    #pragma unroll
    for (int t = 0; t < 4; ++t) acc[t] = 0.f;
    const unsigned short* Arow = As + (rg * 16 + l15) * 136 + quad * 8;
    const unsigned short* Brow = Bt + l15 * 136 + quad * 8;
    #pragma unroll
    for (int ks = 0; ks < 4; ++ks) {
        short8 a = *(const short8*)(Arow + ks * 32);
        #pragma unroll
        for (int tt = 0; tt < 4; ++tt) {
            short8 b = *(const short8*)(Brow + (cg * 4 + tt) * 16 * 136 + ks * 32);
            acc[tt] = __builtin_amdgcn_mfma_f32_16x16x32_bf16(a, b, acc[tt], 0, 0, 0);
        }
    }
    __syncthreads();   // all waves done reading Bt/As; Cs may overwrite

    #pragma unroll
    for (int tt = 0; tt < 4; ++tt)
        #pragma unroll
        for (int r = 0; r < 4; ++r)
            Cs[(rg * 16 + quad * 4 + r) * 132 + (cg * 4 + tt) * 16 + l15] = acc[tt][r];

    // attention dots: wave covers cols (cg*4+tt)*16+l15; for H=2 head == cg exactly
    float ds[4] = {0.f, 0.f, 0.f, 0.f}, dd[4] = {0.f, 0.f, 0.f, 0.f};
    #pragma unroll
    for (int tt = 0; tt < 4; ++tt) {
        int cc = (cg * 4 + tt) * 16 + l15;
        float as_ = att_s[cc], ad_ = att_d[cc];
        #pragma unroll
        for (int r = 0; r < 4; ++r) {
            ds[r] = fmaf(acc[tt][r], as_, ds[r]);
            dd[r] = fmaf(acc[tt][r], ad_, dd[r]);
        }
    }
    #pragma unroll
    for (int off = 1; off < 16; off <<= 1) {
        #pragma unroll
        for (int r = 0; r < 4; ++r) {
            ds[r] += __shfl_xor(ds[r], off);
            dd[r] += __shfl_xor(dd[r], off);
        }
    }
    if (l15 == 0) {
        #pragma unroll
        for (int r = 0; r < 4; ++r) {
            int rr = rg * 16 + quad * 4 + r;
            int row = row0 + rr;
            if (H == 2) {
                if (row < NN) {
                    a_src[row * 2 + cg] = ds[r];
                    a_dst[row * 2 + cg] = dd[r];
                }
            } else {
                psum[cg * 64 + rr] = ds[r];
                psum[128 + cg * 64 + rr] = dd[r];
            }
        }
    }
    __syncthreads();

    if (H == 1 && tid < 64) {
        int row = row0 + tid;
        if (row < NN) {
            a_src[row] = psum[tid] + psum[64 + tid];
            a_dst[row] = psum[128 + tid] + psum[192 + tid];
        }
    }

    // ---- coalesced readout: float4 LDS reads, ushort4 global stores ----
    {
        int sub = tid & 31, rq = tid >> 5;
        int c4 = sub * 4;
        unsigned short* Hp = (unsigned short*)Hout;
        #pragma unroll
        for (int i = 0; i < 4; ++i) {
            int r = i * 16 + rq;
            int row = row0 + r;
            if (row < NN) {
                float4 cv = *(const float4*)&Cs[r * 132 + c4];
                ushort4 pk;
                pk.x = f2bf(cv.x); pk.y = f2bf(cv.y);
                pk.z = f2bf(cv.z); pk.w = f2bf(cv.w);
                *(ushort4*)&Hp[(size_t)row * DD + c4] = pk;
            }
        }
    }
}

template <int H, bool LN, typename XT>
__global__ __launch_bounds__(512) void gemm_attn(const XT* __restrict__ X,
                                                 const float* __restrict__ W,
                                                 const float* __restrict__ att_s,
                                                 const float* __restrict__ att_d,
                                                 const float2* __restrict__ pstats,
                                                 const float* __restrict__ lnw,
                                                 const float* __restrict__ lnb,
                                                 bf16* __restrict__ Hout,
                                                 float* __restrict__ a_src,
                                                 float* __restrict__ a_dst) {
    gemm_attn_body<H, LN, XT>(blockIdx.x, X, W, att_s, att_d, pstats, lnw, lnb,
                              Hout, a_src, a_dst);
}

// ===== fused: CSR scatter pass-1 (blocks 0..NB-1) || layer-1 GEMM (blocks NB..NB+GB-1) =====
// The two are data-independent. Branch is block-uniform so per-branch barriers are safe.
__global__ __launch_bounds__(512) void scatter_gemm1(const int* __restrict__ ei,
                                                     const int* __restrict__ offs,
                                                     unsigned* __restrict__ tmp,
                                                     const float* __restrict__ X,
                                                     const float* __restrict__ W,
                                                     const float* __restrict__ att_s,
                                                     const float* __restrict__ att_d,
                                                     bf16* __restrict__ Hout,
                                                     float* __restrict__ a_src,
                                                     float* __restrict__ a_dst) {
    if (blockIdx.x < NB) {
        __shared__ int lofs[NBKT];
        int tid = threadIdx.x;
        for (int t = tid; t < NBKT; t += 512) lofs[t] = offs[t * NB + blockIdx.x];
        __syncthreads();
        int base = blockIdx.x * EPB;
        #pragma unroll
        for (int j = 0; j < (EPB + 2047) / 2048; ++j) {
            int off = (j * 512 + tid) * 4;
            if (off < EPB) {
                int i4 = base + off;
                if (i4 < EE) {
                    int4 s4 = *(const int4*)&ei[i4];
                    int4 d4 = *(const int4*)&ei[EE + i4];
                    unsigned k0 = ((unsigned)d4.x << 16) | (unsigned)s4.x;
                    unsigned k1 = ((unsigned)d4.y << 16) | (unsigned)s4.y;
                    unsigned k2 = ((unsigned)d4.z << 16) | (unsigned)s4.z;
                    unsigned k3 = ((unsigned)d4.w << 16) | (unsigned)s4.w;
                    tmp[atomicAdd(&lofs[(unsigned)d4.x >> 8], 1)] = k0;
                    tmp[atomicAdd(&lofs[(unsigned)d4.y >> 8], 1)] = k1;
                    tmp[atomicAdd(&lofs[(unsigned)d4.z >> 8], 1)] = k2;
                    tmp[atomicAdd(&lofs[(unsigned)d4.w >> 8], 1)] = k3;
                }
            }
        }
    } else {
        gemm_attn_body<2, false, float>(blockIdx.x - NB, X, W, att_s, att_d,
                                        nullptr, nullptr, nullptr, Hout, a_src, a_dst);
    }
}

// ============ GAT softmax + aggregate: HALF-WAVE PER NODE, 16-lane rows ==============
// Lane sl owns 8 cols (c8=(sl&15)*8, uint4=16B loads); parity half=sl>>4 owns
// alternating edges; cross-parity shfl_xor(16) sums; each lane stores its 16B slice.
// Padding edges carry weight 0 (exact). This is the measured-best gather structure.
// Round-6 lesson (falsified alternative): column-half phasing does NOT reduce FETCH —
// the 85 MB/pass is compulsory first-touch misses per XCD (~43K distinct rows x 256 B
// x 8 XCDs); dst-side phasing/reordering cannot reduce it for a random graph.
// pstats: ONE float2 per BLOCK; reduced by CONSUMER (round-1 lesson: no producer fences).
template <int H, typename OT>
__global__ __launch_bounds__(256) void gat_agg(const int* __restrict__ row_ptr,
                                               const unsigned* __restrict__ col,
                                               const bf16* __restrict__ Hin,
                                               const float* __restrict__ a_src,
                                               const float* __restrict__ a_dst,
                                               const float* __restrict__ bias,
                                               OT* __restrict__ Out,
                                               float2* __restrict__ pstats) {
    int tid = threadIdx.x;
    int sl = tid & 31;
    int hw = tid >> 5;
    int n = blockIdx.x * 8 + hw;
    int half = sl >> 4;                 // edge parity owned by this lane
    int c8 = (sl & 15) * 8;             // 8 cols per lane
    const int headL = (H == 2) ? ((sl & 15) >> 3) : 0;   // cols 0-63 head0, 64-127 head1

    int beg = row_ptr[n], end = row_ptr[n + 1];
    int deg = end - beg;

    float ad0 = a_dst[n * H + 0];
    float ad1 = (H == 2) ? a_dst[n * H + 1] : 0.f;
    const ushort* Hp = (const ushort*)Hin + c8;

    float acc[8] = {0.f, 0.f, 0.f, 0.f, 0.f, 0.f, 0.f, 0.f};
    float dl0 = 0.f, dl1 = 0.f;

    for (int base = 0; base < deg; base += 32) {
        int ecnt = min(32, deg - base);
        int sv = 0; float w0v = 0.f, w1v = 0.f;
        if (sl < ecnt) {
            sv = (int)(col[beg + base + sl] & 0xffffu);
            if (H == 2) {
                float2 av = *(const float2*)&a_src[sv * 2];
                float e0 = av.x + ad0; e0 = (e0 > 0.f) ? e0 : NEG * e0;
                float e1 = av.y + ad1; e1 = (e1 > 0.f) ? e1 : NEG * e1;
                w0v = __expf(e0); w1v = __expf(e1);
                dl0 += w0v; dl1 += w1v;
            } else {
                float e0 = a_src[sv] + ad0; e0 = (e0 > 0.f) ? e0 : NEG * e0;
                w0v = __expf(e0);
                dl0 += w0v;
            }
        }
        int ecnt16 = (ecnt + 15) & ~15;   // 16 or 32; padding: sv=0 (hot row), w=0 (exact)
        for (int j = 0; j < ecnt16; j += 16) {
            int s[8]; uint4 h[8]; float ww[8];
            #pragma unroll
            for (int q = 0; q < 8; ++q) s[q] = __shfl(sv, j + 2 * q + half, 32);
            #pragma unroll
            for (int q = 0; q < 8; ++q) h[q] = *(const uint4*)(Hp + (size_t)s[q] * DD);
            #pragma unroll
            for (int q = 0; q < 8; ++q) {
                int u = j + 2 * q + half;
                if (H == 2) {
                    float a0 = __shfl(w0v, u, 32), b0 = __shfl(w1v, u, 32);
                    ww[q] = headL ? b0 : a0;
                } else {
                    ww[q] = __shfl(w0v, u, 32);
                }
            }
            #pragma unroll
            for (int q = 0; q < 8; ++q) {
                acc[0] = fmaf(ww[q], bflo(h[q].x), acc[0]);
                acc[1] = fmaf(ww[q], bfhi(h[q].x), acc[1]);
                acc[2] = fmaf(ww[q], bflo(h[q].y), acc[2]);
                acc[3] = fmaf(ww[q], bfhi(h[q].y), acc[3]);
                acc[4] = fmaf(ww[q], bflo(h[q].z), acc[4]);
                acc[5] = fmaf(ww[q], bfhi(h[q].z), acc[5]);
                acc[6] = fmaf(ww[q], bflo(h[q].w), acc[6]);
                acc[7] = fmaf(ww[q], bfhi(h[q].w), acc[7]);
            }
        }
    }

    // cross-parity sum: lanes sl and sl^16 cover same cols, complementary edges
    #pragma unroll
    for (int k = 0; k < 8; ++k) acc[k] += __shfl_xor(acc[k], 16, 32);

    #pragma unroll
    for (int off = 1; off < 32; off <<= 1) {
        dl0 += __shfl_xor(dl0, off);
        if (H == 2) dl1 += __shfl_xor(dl1, off);
    }

    // implicit self-loop
    float e0 = a_src[n * H + 0] + ad0; e0 = (e0 > 0.f) ? e0 : NEG * e0;
    float ws0 = __expf(e0);
    float ws1 = 0.f;
    if (H == 2) {
        float e1 = a_src[n * H + 1] + ad1; e1 = (e1 > 0.f) ? e1 : NEG * e1;
        ws1 = __expf(e1);
    }
    float den = (H == 2 && headL) ? (dl1 + ws1) : (dl0 + ws0);
    float wself = (H == 2 && headL) ? ws1 : ws0;
    float rinv = 1.f / (den + 1e-16f);
    uint4 hs = *(const uint4*)(Hp + (size_t)n * DD);
    acc[0] = fmaf(wself, bflo(hs.x), acc[0]);
    acc[1] = fmaf(wself, bfhi(hs.x), acc[1]);
    acc[2] = fmaf(wself, bflo(hs.y), acc[2]);
    acc[3] = fmaf(wself, bfhi(hs.y), acc[3]);
    acc[4] = fmaf(wself, bflo(hs.z), acc[4]);
    acc[5] = fmaf(wself, bfhi(hs.z), acc[5]);
    acc[6] = fmaf(wself, bflo(hs.w), acc[6]);
    acc[7] = fmaf(wself, bfhi(hs.w), acc[7]);

    int b0i = half * 4;
    float4 bi = *(const float4*)&bias[c8 + b0i];
    float4 o;
    o.x = acc[b0i + 0] * rinv + bi.x;
    o.y = acc[b0i + 1] * rinv + bi.y;
    o.z = acc[b0i + 2] * rinv + bi.z;
    o.w = acc[b0i + 3] * rinv + bi.w;
    store4(Out, (size_t)n * DD + c8 + b0i, o);

    // LN partials: each lane's 4 written cols -> half-wave covers all 128 exactly once
    float t1 = o.x + o.y + o.z + o.w;
    float t2 = o.x * o.x + o.y * o.y + o.z * o.z + o.w * o.w;
    #pragma unroll
    for (int off = 1; off < 32; off <<= 1) {
        t1 += __shfl_xor(t1, off);
        t2 += __shfl_xor(t2, off);
    }
    __shared__ float2 ps[8];
    if (sl == 0) ps[hw] = make_float2(t1, t2);
    __syncthreads();
    if (tid == 0) {
        float a = 0.f, b = 0.f;
        #pragma unroll
        for (int k = 0; k < 8; ++k) { a += ps[k].x; b += ps[k].y; }
        pstats[blockIdx.x] = make_float2(a, b);
    }
}

// -------- deterministic single-block reduce of per-BLOCK LN partials (AB entries) ---------
// (kept for stats2 only: simpleconv has 6250 blocks; prologue-reduce there = 312 MB reads)
__global__ __launch_bounds__(1024) void reduce_stats_kernel(const float2* __restrict__ pstats,
                                                            double* __restrict__ stats) {
    int tid = threadIdx.x, lane = tid & 63, wv = tid >> 6;
    double s1 = 0.0, s2 = 0.0;
    for (int i = tid; i < AB; i += 1024) {
        float2 v = pstats[i];
        s1 += (double)v.x; s2 += (double)v.y;
    }
    for (int off = 32; off; off >>= 1) {
        s1 += __shfl_xor(s1, off);
        s2 += __shfl_xor(s2, off);
    }
    __shared__ double w1[16], w2[16];
    if (lane == 0) { w1[wv] = s1; w2[wv] = s2; }
    __syncthreads();
    if (tid == 0) {
        double a = 0.0, b = 0.0;
        for (int i = 0; i < 16; ++i) { a += w1[i]; b += w2[i]; }
        stats[0] = a; stats[1] = b;
    }
}

// ======== SimpleConv(mean) + LN2 affine + residual + relu: 16-lane rows =============
// Same gather structure as gat_agg (ww = 1 real / 0 pad).
__global__ __launch_bounds__(256) void simpleconv_kernel(const int* __restrict__ row_ptr,
                                                         const unsigned* __restrict__ col,
                                                         const bf16* __restrict__ Hin,
                                                         const float* __restrict__ X,
                                                         const double* __restrict__ stats,
                                                         const float* __restrict__ lnw,
                                                         const float* __restrict__ lnb,
                                                         float* __restrict__ Out) {
    int tid = threadIdx.x;
    int sl = tid & 31;
    int n = blockIdx.x * 8 + (tid >> 5);
    int half = sl >> 4;
    int c8 = (sl & 15) * 8;
    int beg = row_ptr[n], end = row_ptr[n + 1];
    int deg = end - beg;
    const ushort* Hp = (const ushort*)Hin + c8;

    float acc[8] = {0.f, 0.f, 0.f, 0.f, 0.f, 0.f, 0.f, 0.f};
    for (int base = 0; base < deg; base += 32) {
        int ecnt = min(32, deg - base);
        int sv = 0;
        if (sl < ecnt) sv = (int)(col[beg + base + sl] & 0xffffu);
        int ecnt16 = (ecnt + 15) & ~15;
        for (int j = 0; j < ecnt16; j += 16) {
            int s[8]; uint4 h[8];
            #pragma unroll
            for (int q = 0; q < 8; ++q) s[q] = __shfl(sv, j + 2 * q + half, 32);
            #pragma unroll
            for (int q = 0; q < 8; ++q) h[q] = *(const uint4*)(Hp + (size_t)s[q] * DD);
            #pragma unroll
            for (int q = 0; q < 8; ++q) {
                float ww = (j + 2 * q + half < ecnt) ? 1.f : 0.f;
                acc[0] = fmaf(ww, bflo(h[q].x), acc[0]);
                acc[1] = fmaf(ww, bfhi(h[q].x), acc[1]);
                acc[2] = fmaf(ww, bflo(h[q].y), acc[2]);
                acc[3] = fmaf(ww, bfhi(h[q].y), acc[3]);
                acc[4] = fmaf(ww, bflo(h[q].z), acc[4]);
                acc[5] = fmaf(ww, bfhi(h[q].z), acc[5]);
                acc[6] = fmaf(ww, bflo(h[q].w), acc[6]);
                acc[7] = fmaf(ww, bfhi(h[q].w), acc[7]);
            }
        }
    }

    // cross-parity sum
    #pragma unroll
    for (int k = 0; k < 8; ++k) acc[k] += __shfl_xor(acc[k], 16, 32);

    const double M = (double)NN * DD;
    double mean_d = stats[0] / M;
    double var_d = stats[1] / M - mean_d * mean_d;
    float mean2 = (float)mean_d;
    float inv2 = rsqrtf((float)var_d + EPSL);
    float rc = 1.f / (float)((deg > 0) ? deg : 1);
    int b0i = half * 4;
    float4 xr = *(const float4*)&X[(size_t)n * DD + c8 + b0i];
    float4 o;
    if (deg > 0) {
        float4 lw = *(const float4*)&lnw[c8 + b0i];
        float4 lb = *(const float4*)&lnb[c8 + b0i];
        o.x = (acc[b0i + 0] * rc - mean2) * inv2 * lw.x + lb.x;
        o.y = (acc[b0i + 1] * rc - mean2) * inv2 * lw.y + lb.y;
        o.z = (acc[b0i + 2] * rc - mean2) * inv2 * lw.z + lb.z;
        o.w = (acc[b0i + 3] * rc - mean2) * inv2 * lw.w + lb.w;
    } else {
        o.x = o.y = o.z = o.w = 0.f;
    }
    o.x = fmaxf(o.x + xr.x, 0.f);
    o.y = fmaxf(o.y + xr.y, 0.f);
    o.z = fmaxf(o.z + xr.z, 0.f);
    o.w = fmaxf(o.w + xr.w, 0.f);
    *(float4*)&Out[(size_t)n * DD + c8 + b0i] = o;
}

extern "C" void kernel_launch(void* const* d_in, const int* in_sizes, int n_in,
                              void* d_out, int out_size, void* d_ws, size_t ws_size,
                              hipStream_t stream) {
    const float* x    = (const float*)d_in[0];
    const int*   ei   = (const int*)d_in[1];
    const float* W1   = (const float*)d_in[2];
    const float* as1  = (const float*)d_in[3];
    const float* ad1  = (const float*)d_in[4];
    const float* b1   = (const float*)d_in[5];
    const float* ln1w = (const float*)d_in[6];
    const float* ln1b = (const float*)d_in[7];
    const float* W2   = (const float*)d_in[8];
    const float* as2  = (const float*)d_in[9];
    const float* ad2  = (const float*)d_in[10];
    const float* b2   = (const float*)d_in[11];
    const float* ln2w = (const float*)d_in[12];
    const float* ln2b = (const float*)d_in[13];
    float* out = (float*)d_out;

    char* p = (char*)d_ws;
    auto alloc = [&](size_t bytes) {
        void* r = (void*)p;
        p += (bytes + 255) & ~(size_t)255;
        return r;
    };
    unsigned* tmp     = (unsigned*)alloc((size_t)EE * 4);
    unsigned* col     = (unsigned*)alloc((size_t)EE * 4);
    int*      histG   = (int*)alloc((size_t)HM * 4);
    int*      offs    = (int*)alloc((size_t)HM * 4);
    int*      bstart  = (int*)alloc((size_t)(NBKT + 1) * 4);
    int*      row_ptr = (int*)alloc((size_t)(NN + 256) * 4);
    double*   stats2  = (double*)alloc(16);
    float2*   pstats  = (float2*)alloc((size_t)AB * 8);
    bf16*     bufA    = (bf16*)alloc((size_t)NN * DD * 2);   // h1, later h2
    bf16*     bufB    = (bf16*)alloc((size_t)NN * DD * 2);   // out1, later out2
    float*    aS1     = (float*)alloc((size_t)NN * 2 * 4);
    float*    aD1     = (float*)alloc((size_t)NN * 2 * 4);
    float*    aS2     = (float*)alloc((size_t)NN * 4);
    float*    aD2     = (float*)alloc((size_t)NN * 4);

    const int GB = (NN + GROWS - 1) / GROWS;   // 782

    // ---- CSR build (bucket sort); gemm1 overlapped with scatter pass ----
    hist_kernel<<<NB, 256, 0, stream>>>(ei, histG);
    scan_hist_kernel<<<1, 1024, 0, stream>>>(histG, offs, bstart);
    scatter_gemm1<<<NB + GB, 512, 0, stream>>>(ei, offs, tmp,
                                               x, W1, as1, ad1, bufA, aS1, aD1);
    bucket_sort_kernel<<<NBKT, 512, 0, stream>>>(tmp, bstart, col, row_ptr);

    // layer 1 aggregate: GATConv(128 -> 64, heads=2, concat)
    gat_agg<2, bf16><<<AB, 256, 0, stream>>>(row_ptr, col, bufA, aS1, aD1, b1, bufB, pstats);

    // layer 2: GATConv(128 -> 128, heads=1); LN1 stats reduced in-prologue from pstats
    gemm_attn<1, true, bf16><<<GB, 512, 0, stream>>>(bufB, W2, as2, ad2,
                                                     pstats, ln1w, ln1b,
                                                     bufA, aS2, aD2);
    gat_agg<1, bf16><<<AB, 256, 0, stream>>>(row_ptr, col, bufA, aS2, aD2, b2, bufB, pstats);
    reduce_stats_kernel<<<1, 1024, 0, stream>>>(pstats, stats2);

    // SimpleConv mean over original edges + LN2 affine + residual + relu (fused)
    simpleconv_kernel<<<AB, 256, 0, stream>>>(row_ptr, col, bufB, x,
                                              stats2, ln2w, ln2b, out);
}